// Round 3
// baseline (1287.680 us; speedup 1.0000x reference)
//
#include <hip/hip_runtime.h>

#define T_STEPS 1024
#define NZV 60          // valid z width
#define H 128
#define NY 8
#define NU 4
#define ZSTR 72         // padded LDS stride (shorts) for z (144B rows)
#define HSTR 136        // padded LDS stride (shorts) for h1/h2 (272B rows)

typedef __attribute__((ext_vector_type(8))) short bf16x8;
typedef __attribute__((ext_vector_type(4))) short bf16x4;
typedef __attribute__((ext_vector_type(4))) float f32x4;

__device__ __forceinline__ unsigned short f2bf(float x) {
    unsigned u = __float_as_uint(x);
    u += 0x7FFFu + ((u >> 16) & 1u);
    return (unsigned short)(u >> 16);
}

// tanh(x) = 1 - 2/(exp(2x)+1); exp2 saturates to inf/0 so no clamp needed.
__device__ __forceinline__ float tanh_fast(float x) {
    float e = __builtin_amdgcn_exp2f(x * 2.8853900817779268f);
    return fmaf(-2.0f, __builtin_amdgcn_rcpf(e + 1.0f), 1.0f);
}

__global__ __launch_bounds__(512, 4)
void cstr_scan_kernel(const float* __restrict__ u_g, const float* __restrict__ z0_g,
                      const float* __restrict__ W1, const float* __restrict__ b1,
                      const float* __restrict__ W2, const float* __restrict__ b2,
                      const float* __restrict__ W3, const float* __restrict__ b3,
                      float* __restrict__ out) {
    __shared__ unsigned short zbuf[2][16][ZSTR];
    __shared__ unsigned short h1s[16][HSTR];
    __shared__ unsigned short h2s[16][HSTR];
    __shared__ f32x4 ypart[8][64];

    const int tid   = threadIdx.x;
    const int wid   = tid >> 6;          // 0..7 (n-tile owner)
    const int lane  = tid & 63;
    const int b0    = blockIdx.x * 16;   // batch row base
    const int col   = lane & 15;         // MFMA col / A row
    const int kg    = lane >> 4;         // 0..3 (k-group)
    const int wrow0 = kg * 4;            // C-frag row base
    const int urow  = lane >> 2;         // u/z-shift row
    const int uc    = lane & 3;
    const int nbase = wid * 16;          // this wave's hidden-col base

    // ---- preload weight fragments for this wave's 16 hidden cols ----
    bf16x8 w1f[2], w2f[4], w3f;
    const float b1v = b1[nbase + col];
    const float b2v = b2[nbase + col];
    const float b3seed = (wid == 0 && col < NY) ? b3[col] : 0.f;

#pragma unroll
    for (int kc = 0; kc < 2; ++kc) {
        bf16x8 v;
#pragma unroll
        for (int j = 0; j < 8; ++j) {
            int k = kc * 32 + kg * 8 + j;
            float w = (k < NZV) ? W1[k * H + nbase + col] : 0.f;
            v[j] = (short)f2bf(w);
        }
        w1f[kc] = v;
    }
#pragma unroll
    for (int kc = 0; kc < 4; ++kc) {
        bf16x8 v;
#pragma unroll
        for (int j = 0; j < 8; ++j) {
            int k = kc * 32 + kg * 8 + j;
            v[j] = (short)f2bf(W2[k * H + nbase + col]);
        }
        w2f[kc] = v;
    }
    {
        bf16x8 v = { 0, 0, 0, 0, 0, 0, 0, 0 };
        if (kg < 2) {
#pragma unroll
            for (int j = 0; j < 8; ++j) {
                int k = nbase + kg * 8 + j;   // this wave's K-window of GEMM3
                float w = (col < NY) ? W3[k * NY + col] : 0.f;
                v[j] = (short)f2bf(w);
            }
        }
        w3f = v;
    }

    // ---- init z state (bf16) ----
    {
        unsigned short* zs = &zbuf[0][0][0];
        for (int i = tid; i < 2 * 16 * ZSTR; i += 512) zs[i] = 0;
        __syncthreads();
        for (int i = tid; i < 16 * NZV; i += 512) {
            int r = i / NZV, c = i - r * NZV;
            zbuf[0][r][c] = f2bf(z0_g[(size_t)(b0 + r) * NZV + c]);
        }
        __syncthreads();
    }

    float ureg = 0.f, ureg_n = 0.f;
    if (wid == 7)
        ureg = u_g[(size_t)(b0 + urow) * (T_STEPS * NU) + uc];

    f32x4 yprev = { 0.f, 0.f, 0.f, 0.f };

    int cur = 0;
#pragma unroll 1
    for (int t = 0; t < T_STEPS; ++t) {
        const int nxt = cur ^ 1;

        // wave0: deferred global y-store for step t-1 (overlaps phase 1)
        if (wid == 0 && t > 0 && col < NY) {
#pragma unroll
            for (int r = 0; r < 4; ++r)
                out[(size_t)(b0 + wrow0 + r) * (T_STEPS * NY) + (size_t)(t - 1) * NY + col] = yprev[r];
        }
        // wave7: prefetch u for step t+1
        if (wid == 7 && t + 1 < T_STEPS)
            ureg_n = u_g[(size_t)(b0 + urow) * (T_STEPS * NU) + (size_t)(t + 1) * NU + uc];

        // ---- phase 1: GEMM1 (z @ W1) on this wave's 16 cols ----
        bf16x8 za0 = *(const bf16x8*)&zbuf[cur][col][kg * 8];
        bf16x8 za1 = *(const bf16x8*)&zbuf[cur][col][32 + kg * 8];
        f32x4 c1 = { b1v, b1v, b1v, b1v };
        c1 = __builtin_amdgcn_mfma_f32_16x16x32_bf16(za0, w1f[0], c1, 0, 0, 0);
        c1 = __builtin_amdgcn_mfma_f32_16x16x32_bf16(za1, w1f[1], c1, 0, 0, 0);
#pragma unroll
        for (int r = 0; r < 4; ++r)
            h1s[wrow0 + r][nbase + col] = f2bf(tanh_fast(c1[r]));

        // wave7: z shift cur->nxt + u insert (disjoint from y slot)
        if (wid == 7) {
            bf16x4 m0 = *(const bf16x4*)&zbuf[cur][urow][8 + 8 * uc];
            bf16x4 m1 = *(const bf16x4*)&zbuf[cur][urow][12 + 8 * uc];
            bf16x4 m2 = *(const bf16x4*)&zbuf[cur][urow][44 + 4 * uc];
            *(bf16x4*)&zbuf[nxt][urow][8 * uc]      = m0;
            *(bf16x4*)&zbuf[nxt][urow][8 * uc + 4]  = m1;
            *(bf16x4*)&zbuf[nxt][urow][40 + 4 * uc] = m2;
            zbuf[nxt][urow][56 + uc] = f2bf(ureg);
        }
        __syncthreads();   // Bb: h1 complete, z[nxt] (minus y) complete

        // ---- phase 2: GEMM2 (h1 @ W2, full K) + own GEMM3 partial ----
        bf16x8 ha0 = *(const bf16x8*)&h1s[col][0 * 32 + kg * 8];
        bf16x8 ha1 = *(const bf16x8*)&h1s[col][1 * 32 + kg * 8];
        bf16x8 ha2 = *(const bf16x8*)&h1s[col][2 * 32 + kg * 8];
        bf16x8 ha3 = *(const bf16x8*)&h1s[col][3 * 32 + kg * 8];
        f32x4 a0 = { b2v, b2v, b2v, b2v };
        f32x4 a1 = { 0.f, 0.f, 0.f, 0.f };
        a0 = __builtin_amdgcn_mfma_f32_16x16x32_bf16(ha0, w2f[0], a0, 0, 0, 0);
        a1 = __builtin_amdgcn_mfma_f32_16x16x32_bf16(ha1, w2f[1], a1, 0, 0, 0);
        a0 = __builtin_amdgcn_mfma_f32_16x16x32_bf16(ha2, w2f[2], a0, 0, 0, 0);
        a1 = __builtin_amdgcn_mfma_f32_16x16x32_bf16(ha3, w2f[3], a1, 0, 0, 0);
        f32x4 c2 = a0 + a1;
#pragma unroll
        for (int r = 0; r < 4; ++r)
            h2s[wrow0 + r][nbase + col] = f2bf(tanh_fast(c2[r]));

        // same-wave readback of own 16-col h2 chunk as GEMM3 A-frag
        // (K window [0,16) real, [16,32) zero via kg>=2 lanes)
        bf16x8 af = { 0, 0, 0, 0, 0, 0, 0, 0 };
        if (kg < 2)
            af = *(const bf16x8*)&h2s[col][nbase + kg * 8];
        f32x4 yp = { b3seed, b3seed, b3seed, b3seed };
        yp = __builtin_amdgcn_mfma_f32_16x16x32_bf16(af, w3f, yp, 0, 0, 0);
        ypart[wid][lane] = yp;
        __syncthreads();   // Bc: all ypart visible

        // ---- phase 3: wave0 reduces partials, writes y into z[nxt] ----
        if (wid == 0) {
            f32x4 y = ypart[0][lane];
#pragma unroll
            for (int w = 1; w < 8; ++w) y = y + ypart[w][lane];
            yprev = y;
            if (col < NY) {
#pragma unroll
                for (int r = 0; r < 4; ++r)
                    zbuf[nxt][wrow0 + r][32 + col] = f2bf(y[r]);
            }
        }
        __syncthreads();   // Ba: z[nxt] fully valid

        cur = nxt;
        ureg = ureg_n;
    }

    // final y-store (t = T-1)
    if (wid == 0 && col < NY) {
#pragma unroll
        for (int r = 0; r < 4; ++r)
            out[(size_t)(b0 + wrow0 + r) * (T_STEPS * NY) + (size_t)(T_STEPS - 1) * NY + col] = yprev[r];
    }
}

extern "C" void kernel_launch(void* const* d_in, const int* in_sizes, int n_in,
                              void* d_out, int out_size, void* d_ws, size_t ws_size,
                              hipStream_t stream) {
    (void)in_sizes; (void)n_in; (void)d_ws; (void)ws_size; (void)out_size;
    const float* u  = (const float*)d_in[0];
    const float* z0 = (const float*)d_in[1];
    const float* W1 = (const float*)d_in[2];
    const float* b1 = (const float*)d_in[3];
    const float* W2 = (const float*)d_in[4];
    const float* b2 = (const float*)d_in[5];
    const float* W3 = (const float*)d_in[6];
    const float* b3 = (const float*)d_in[7];
    float* out = (float*)d_out;

    dim3 grid(8192 / 16);   // 512 blocks x 8 waves; 16 batch rows/block
    dim3 block(512);
    cstr_scan_kernel<<<grid, block, 0, stream>>>(u, z0, W1, b1, W2, b2, W3, b3, out);
}